// Round 1
// baseline (835.977 us; speedup 1.0000x reference)
//
#include <hip/hip_runtime.h>
#include <math.h>

// Problem constants: B=4, S=1024, F=256, H=8, F*H=2048, SCALE=16.0
#define SQ 1024
#define FQ 256
#define FH 2048

// GEMM tiling: 64x64 tile, BK=32, 256 threads (16x16), 4x4 per thread.
#define BK 32
#define PADL 68   // LDS leading-dim pad (mult of 4 -> float4-aligned rows)

// ---------------------------------------------------------------------------
// Kernel 1: QKV projection. C(4096x2048) = X(4096x256) @ W(256x2048),
// scattered into (b,h,s,f) layout: col c -> h=c&7, f=c>>3.
// ---------------------------------------------------------------------------
__global__ __launch_bounds__(256) void proj_kernel(const float* __restrict__ A,
                                                   const float* __restrict__ W,
                                                   float* __restrict__ O) {
    __shared__ float As[BK][PADL];   // As[kk][row]
    __shared__ float Bs[BK][PADL];   // Bs[kk][col]
    const int t  = threadIdx.x;
    const int tx = t & 15, ty = t >> 4;
    const int row0 = blockIdx.y * 64, col0 = blockIdx.x * 64;
    float acc[4][4] = {};
    for (int k0 = 0; k0 < 256; k0 += BK) {
        __syncthreads();
        // A: 64 rows x 32 k, float4 per thread x2 (transposed store)
        {
            int q = t;
            int r = q >> 3, kf = (q & 7) << 2;
            float4 v = *(const float4*)(A + (size_t)(row0 + r) * 256 + k0 + kf);
            As[kf + 0][r] = v.x; As[kf + 1][r] = v.y; As[kf + 2][r] = v.z; As[kf + 3][r] = v.w;
            q = t + 256; r = q >> 3; kf = (q & 7) << 2;
            v = *(const float4*)(A + (size_t)(row0 + r) * 256 + k0 + kf);
            As[kf + 0][r] = v.x; As[kf + 1][r] = v.y; As[kf + 2][r] = v.z; As[kf + 3][r] = v.w;
        }
        // W: 32 k-rows x 64 cols
        {
            int q = t;
            int kk = q >> 4, cf = (q & 15) << 2;
            *(float4*)&Bs[kk][cf] = *(const float4*)(W + (size_t)(k0 + kk) * FH + col0 + cf);
            q = t + 256; kk = q >> 4; cf = (q & 15) << 2;
            *(float4*)&Bs[kk][cf] = *(const float4*)(W + (size_t)(k0 + kk) * FH + col0 + cf);
        }
        __syncthreads();
#pragma unroll
        for (int kk = 0; kk < BK; ++kk) {
            float4 a = *(const float4*)&As[kk][ty * 4];
            float4 b = *(const float4*)&Bs[kk][tx * 4];
            float av[4] = {a.x, a.y, a.z, a.w};
            float bv[4] = {b.x, b.y, b.z, b.w};
#pragma unroll
            for (int i = 0; i < 4; ++i)
#pragma unroll
                for (int j = 0; j < 4; ++j) acc[i][j] += av[i] * bv[j];
        }
    }
#pragma unroll
    for (int i = 0; i < 4; ++i) {
        int gr = row0 + ty * 4 + i;
        int bb = gr >> 10, srow = gr & 1023;
#pragma unroll
        for (int j = 0; j < 4; ++j) {
            int cg = col0 + tx * 4 + j;
            int h = cg & 7, f = cg >> 3;
            O[(((size_t)(bb * 8 + h) * SQ + srow) * FQ) + f] = acc[i][j];
        }
    }
}

// ---------------------------------------------------------------------------
// Kernel 2: P = sigmoid(16 * Q_bh @ K_bh^T).  NT GEMM, M=N=1024, K=256.
// Q,K in (b,h,s,f) layout. P plain row-major 1024x1024 per z.
// ---------------------------------------------------------------------------
__global__ __launch_bounds__(256) void qk_kernel(const float* __restrict__ Qb,
                                                 const float* __restrict__ Kb,
                                                 float* __restrict__ P,
                                                 int bh_base) {
    const int bh = bh_base + blockIdx.z;
    const float* Aq = Qb + (size_t)bh * SQ * FQ;
    const float* Bk = Kb + (size_t)bh * SQ * FQ;
    float* Pz = P + (size_t)blockIdx.z * SQ * SQ;
    __shared__ float As[BK][PADL];
    __shared__ float Bs[BK][PADL];
    const int t  = threadIdx.x;
    const int tx = t & 15, ty = t >> 4;
    const int row0 = blockIdx.y * 64, col0 = blockIdx.x * 64;
    float acc[4][4] = {};
    for (int k0 = 0; k0 < 256; k0 += BK) {
        __syncthreads();
        {
            int q = t;
            int r = q >> 3, kf = (q & 7) << 2;
            float4 v = *(const float4*)(Aq + (size_t)(row0 + r) * 256 + k0 + kf);
            As[kf + 0][r] = v.x; As[kf + 1][r] = v.y; As[kf + 2][r] = v.z; As[kf + 3][r] = v.w;
            q = t + 256; r = q >> 3; kf = (q & 7) << 2;
            v = *(const float4*)(Aq + (size_t)(row0 + r) * 256 + k0 + kf);
            As[kf + 0][r] = v.x; As[kf + 1][r] = v.y; As[kf + 2][r] = v.z; As[kf + 3][r] = v.w;
        }
        {   // K rows are the "columns" of B^T: transposed store like A
            int q = t;
            int r = q >> 3, kf = (q & 7) << 2;
            float4 v = *(const float4*)(Bk + (size_t)(col0 + r) * 256 + k0 + kf);
            Bs[kf + 0][r] = v.x; Bs[kf + 1][r] = v.y; Bs[kf + 2][r] = v.z; Bs[kf + 3][r] = v.w;
            q = t + 256; r = q >> 3; kf = (q & 7) << 2;
            v = *(const float4*)(Bk + (size_t)(col0 + r) * 256 + k0 + kf);
            Bs[kf + 0][r] = v.x; Bs[kf + 1][r] = v.y; Bs[kf + 2][r] = v.z; Bs[kf + 3][r] = v.w;
        }
        __syncthreads();
#pragma unroll
        for (int kk = 0; kk < BK; ++kk) {
            float4 a = *(const float4*)&As[kk][ty * 4];
            float4 b = *(const float4*)&Bs[kk][tx * 4];
            float av[4] = {a.x, a.y, a.z, a.w};
            float bv[4] = {b.x, b.y, b.z, b.w};
#pragma unroll
            for (int i = 0; i < 4; ++i)
#pragma unroll
                for (int j = 0; j < 4; ++j) acc[i][j] += av[i] * bv[j];
        }
    }
#pragma unroll
    for (int i = 0; i < 4; ++i)
#pragma unroll
        for (int j = 0; j < 4; ++j) {
            float lg = 16.0f * acc[i][j];
            float sg = 1.0f / (1.0f + expf(-lg));
            Pz[(size_t)(row0 + ty * 4 + i) * SQ + (col0 + tx * 4 + j)] = sg;
        }
}

// ---------------------------------------------------------------------------
// Kernel 3: WV = P @ V_bh.  NN GEMM, M=1024, N=256, K=1024.
// Output scattered to plain (row=b*S+i, col=f*8+h) layout for final GEMM.
// ---------------------------------------------------------------------------
__global__ __launch_bounds__(256) void pv_kernel(const float* __restrict__ P,
                                                 const float* __restrict__ Vb,
                                                 float* __restrict__ WV,
                                                 int bh_base) {
    const int bh = bh_base + blockIdx.z;
    const int bb = bh >> 3, h = bh & 7;
    const float* Ap = P + (size_t)blockIdx.z * SQ * SQ;
    const float* Bv = Vb + (size_t)bh * SQ * FQ;
    __shared__ float As[BK][PADL];
    __shared__ float Bs[BK][PADL];
    const int t  = threadIdx.x;
    const int tx = t & 15, ty = t >> 4;
    const int row0 = blockIdx.y * 64, col0 = blockIdx.x * 64;
    float acc[4][4] = {};
    for (int k0 = 0; k0 < SQ; k0 += BK) {
        __syncthreads();
        {
            int q = t;
            int r = q >> 3, kf = (q & 7) << 2;
            float4 v = *(const float4*)(Ap + (size_t)(row0 + r) * SQ + k0 + kf);
            As[kf + 0][r] = v.x; As[kf + 1][r] = v.y; As[kf + 2][r] = v.z; As[kf + 3][r] = v.w;
            q = t + 256; r = q >> 3; kf = (q & 7) << 2;
            v = *(const float4*)(Ap + (size_t)(row0 + r) * SQ + k0 + kf);
            As[kf + 0][r] = v.x; As[kf + 1][r] = v.y; As[kf + 2][r] = v.z; As[kf + 3][r] = v.w;
        }
        {
            int q = t;
            int kk = q >> 4, cf = (q & 15) << 2;
            *(float4*)&Bs[kk][cf] = *(const float4*)(Bv + (size_t)(k0 + kk) * FQ + col0 + cf);
            q = t + 256; kk = q >> 4; cf = (q & 15) << 2;
            *(float4*)&Bs[kk][cf] = *(const float4*)(Bv + (size_t)(k0 + kk) * FQ + col0 + cf);
        }
        __syncthreads();
#pragma unroll
        for (int kk = 0; kk < BK; ++kk) {
            float4 a = *(const float4*)&As[kk][ty * 4];
            float4 b = *(const float4*)&Bs[kk][tx * 4];
            float av[4] = {a.x, a.y, a.z, a.w};
            float bv[4] = {b.x, b.y, b.z, b.w};
#pragma unroll
            for (int i = 0; i < 4; ++i)
#pragma unroll
                for (int j = 0; j < 4; ++j) acc[i][j] += av[i] * bv[j];
        }
    }
#pragma unroll
    for (int i = 0; i < 4; ++i) {
        int gi = row0 + ty * 4 + i;
#pragma unroll
        for (int j = 0; j < 4; ++j) {
            int f = col0 + tx * 4 + j;
            WV[((size_t)(bb * SQ + gi)) * FH + f * 8 + h] = acc[i][j];
        }
    }
}

// ---------------------------------------------------------------------------
// Kernel 4: out = relu(WV(4096x2048) @ Wo(2048x256)).  NN GEMM.
// ---------------------------------------------------------------------------
__global__ __launch_bounds__(256) void out_kernel(const float* __restrict__ A,
                                                  const float* __restrict__ W,
                                                  float* __restrict__ O) {
    __shared__ float As[BK][PADL];
    __shared__ float Bs[BK][PADL];
    const int t  = threadIdx.x;
    const int tx = t & 15, ty = t >> 4;
    const int row0 = blockIdx.y * 64, col0 = blockIdx.x * 64;
    float acc[4][4] = {};
    for (int k0 = 0; k0 < FH; k0 += BK) {
        __syncthreads();
        {
            int q = t;
            int r = q >> 3, kf = (q & 7) << 2;
            float4 v = *(const float4*)(A + (size_t)(row0 + r) * FH + k0 + kf);
            As[kf + 0][r] = v.x; As[kf + 1][r] = v.y; As[kf + 2][r] = v.z; As[kf + 3][r] = v.w;
            q = t + 256; r = q >> 3; kf = (q & 7) << 2;
            v = *(const float4*)(A + (size_t)(row0 + r) * FH + k0 + kf);
            As[kf + 0][r] = v.x; As[kf + 1][r] = v.y; As[kf + 2][r] = v.z; As[kf + 3][r] = v.w;
        }
        {
            int q = t;
            int kk = q >> 4, cf = (q & 15) << 2;
            *(float4*)&Bs[kk][cf] = *(const float4*)(W + (size_t)(k0 + kk) * FQ + col0 + cf);
            q = t + 256; kk = q >> 4; cf = (q & 15) << 2;
            *(float4*)&Bs[kk][cf] = *(const float4*)(W + (size_t)(k0 + kk) * FQ + col0 + cf);
        }
        __syncthreads();
#pragma unroll
        for (int kk = 0; kk < BK; ++kk) {
            float4 a = *(const float4*)&As[kk][ty * 4];
            float4 b = *(const float4*)&Bs[kk][tx * 4];
            float av[4] = {a.x, a.y, a.z, a.w};
            float bv[4] = {b.x, b.y, b.z, b.w};
#pragma unroll
            for (int i = 0; i < 4; ++i)
#pragma unroll
                for (int j = 0; j < 4; ++j) acc[i][j] += av[i] * bv[j];
        }
    }
#pragma unroll
    for (int i = 0; i < 4; ++i)
#pragma unroll
        for (int j = 0; j < 4; ++j) {
            float v = fmaxf(acc[i][j], 0.0f);
            O[(size_t)(row0 + ty * 4 + i) * FQ + (col0 + tx * 4 + j)] = v;
        }
}

// ---------------------------------------------------------------------------
extern "C" void kernel_launch(void* const* d_in, const int* in_sizes, int n_in,
                              void* d_out, int out_size, void* d_ws, size_t ws_size,
                              hipStream_t stream) {
    const float* x  = (const float*)d_in[0];
    const float* Wq = (const float*)d_in[1];
    const float* Wk = (const float*)d_in[2];
    const float* Wv = (const float*)d_in[3];
    const float* Wo = (const float*)d_in[4];
    float* out = (float*)d_out;

    float* ws    = (float*)d_ws;
    float* qbuf  = ws;                  // 4096*2048 = 8,388,608 floats
    float* kbuf  = qbuf + 8388608;
    float* vbuf  = kbuf + 8388608;
    float* wvbuf = vbuf + 8388608;
    float* pbuf  = wvbuf + 8388608;     // chunk * 1M floats

    // Pick P-chunk (heads per round) from available workspace.
    const size_t baseB = 4ull * 8388608ull * 4ull;  // q,k,v,wv = 128 MiB
    const size_t pbhB  = (size_t)SQ * SQ * 4ull;    // 4 MiB per (b,h)
    int chunk = 1;
    if      (ws_size >= baseB + 32 * pbhB) chunk = 32;
    else if (ws_size >= baseB + 16 * pbhB) chunk = 16;
    else if (ws_size >= baseB +  8 * pbhB) chunk = 8;
    else if (ws_size >= baseB +  4 * pbhB) chunk = 4;
    else if (ws_size >= baseB +  2 * pbhB) chunk = 2;

    dim3 blk(256);
    proj_kernel<<<dim3(32, 64), blk, 0, stream>>>(x, Wq, qbuf);
    proj_kernel<<<dim3(32, 64), blk, 0, stream>>>(x, Wk, kbuf);
    proj_kernel<<<dim3(32, 64), blk, 0, stream>>>(x, Wv, vbuf);
    for (int bh0 = 0; bh0 < 32; bh0 += chunk) {
        qk_kernel<<<dim3(16, 16, chunk), blk, 0, stream>>>(qbuf, kbuf, pbuf, bh0);
        pv_kernel<<<dim3(4, 16, chunk), blk, 0, stream>>>(pbuf, vbuf, wvbuf, bh0);
    }
    out_kernel<<<dim3(4, 64), blk, 0, stream>>>(wvbuf, Wo, out);
}

// Round 2
// 294.703 us; speedup vs baseline: 2.8367x; 2.8367x over previous
//
#include <hip/hip_runtime.h>
#include <math.h>

// Problem: B=4, S=1024, F=256, H=8, FH=2048. SCALE=16 (multiplies logits).
#define SQ 1024
#define FQ 256
#define FH 2048

typedef _Float16 f16;
typedef f16  f16x8 __attribute__((ext_vector_type(8)));
typedef float f32x4 __attribute__((ext_vector_type(4)));

#define LDSPAD 40   // f16 row stride in LDS: 80 B = 20 banks -> only 2-way aliasing (free)

// ---------------------------------------------------------------------------
// Elementwise: fp32 -> f16 (x input). 4 elems/thread.
// ---------------------------------------------------------------------------
__global__ __launch_bounds__(256) void cvt_kernel(const float* __restrict__ in,
                                                  f16* __restrict__ out) {
    int idx = (blockIdx.x * 256 + threadIdx.x) * 4;
    float4 v = *(const float4*)(in + idx);
    out[idx + 0] = (f16)v.x; out[idx + 1] = (f16)v.y;
    out[idx + 2] = (f16)v.z; out[idx + 3] = (f16)v.w;
}

// ---------------------------------------------------------------------------
// Transpose + convert: W (K x N fp32, row-major) -> WT (N x K f16, row-major).
// 32x32 LDS tile. grid = (N/32, K/32), block = 256 (= 32 x 8).
// ---------------------------------------------------------------------------
__global__ __launch_bounds__(256) void transpose_kernel(const float* __restrict__ W,
                                                        f16* __restrict__ WT,
                                                        int K, int N) {
    __shared__ f16 T[32][33];
    const int tx = threadIdx.x & 31, ty = threadIdx.x >> 5;
    const int n0 = blockIdx.x * 32, k0 = blockIdx.y * 32;
#pragma unroll
    for (int i = 0; i < 4; ++i)
        T[ty + i * 8][tx] = (f16)W[(size_t)(k0 + ty + i * 8) * N + n0 + tx];
    __syncthreads();
#pragma unroll
    for (int i = 0; i < 4; ++i)
        WT[(size_t)(n0 + ty + i * 8) * K + k0 + tx] = T[tx][ty + i * 8];
}

// ---------------------------------------------------------------------------
// Core 128x128 MFMA tile, BK=32. 256 threads = 4 waves in 2x2 of 64x64.
// A: row-major [M][K] f16 (lda). Bt: row-major [N][K] f16 (ldb).
// Frag layouts (16x16x32 f16): A[m=lane&15][k=(lane>>4)*8+j]; B mirrored;
// C/D: col=lane&15, row=(lane>>4)*4+reg (dtype-independent, m89-verified).
// ---------------------------------------------------------------------------
__device__ __forceinline__ void gemm128(const f16* __restrict__ A, int lda,
                                        const f16* __restrict__ Bt, int ldb,
                                        int K, f16* As, f16* Bs,
                                        f32x4 acc[4][4], int row0, int col0) {
    const int t = threadIdx.x;
    const int lane = t & 63;
    const int w = t >> 6, wr = w >> 1, wc = w & 1;
    const int lrow = lane & 15, lquad = lane >> 4;

    for (int k0 = 0; k0 < K; k0 += 32) {
        __syncthreads();
        // stage A-tile and Bt-tile: 128 rows x 32 k each; 8-f16 (16 B) chunks.
#pragma unroll
        for (int it = 0; it < 2; ++it) {
            int c = t + it * 256;          // chunk id 0..511
            int r = c >> 2, kc = (c & 3) << 3;
            float4 va = *(const float4*)(A  + (size_t)(row0 + r) * lda + k0 + kc);
            *(float4*)&As[r * LDSPAD + kc] = va;
            float4 vb = *(const float4*)(Bt + (size_t)(col0 + r) * ldb + k0 + kc);
            *(float4*)&Bs[r * LDSPAD + kc] = vb;
        }
        __syncthreads();
        f16x8 af[4], bf[4];
#pragma unroll
        for (int i = 0; i < 4; ++i) {
            af[i] = *(const f16x8*)&As[(wr * 64 + i * 16 + lrow) * LDSPAD + lquad * 8];
            bf[i] = *(const f16x8*)&Bs[(wc * 64 + i * 16 + lrow) * LDSPAD + lquad * 8];
        }
#pragma unroll
        for (int i = 0; i < 4; ++i)
#pragma unroll
            for (int j = 0; j < 4; ++j)
                acc[i][j] = __builtin_amdgcn_mfma_f32_16x16x32_f16(af[i], bf[j], acc[i][j], 0, 0, 0);
    }
}

// ---------------------------------------------------------------------------
// Kernel: QKV projection. C(4096x2048) = xh @ W  (via WT).
// mode 0: scatter to (b,h,s,f) f16.  mode 1 (V): scatter to (b,h,f,s) f16.
// ---------------------------------------------------------------------------
__global__ __launch_bounds__(256) void proj_mfma(const f16* __restrict__ xh,
                                                 const f16* __restrict__ WT,
                                                 f16* __restrict__ O, int mode) {
    __shared__ f16 As[128 * LDSPAD];
    __shared__ f16 Bs[128 * LDSPAD];
    f32x4 acc[4][4] = {};
    const int row0 = blockIdx.y * 128, col0 = blockIdx.x * 128;
    gemm128(xh, FQ, WT, FQ, FQ, As, Bs, acc, row0, col0);

    const int lane = threadIdx.x & 63;
    const int w = threadIdx.x >> 6, wr = w >> 1, wc = w & 1;
#pragma unroll
    for (int i = 0; i < 4; ++i)
#pragma unroll
        for (int r = 0; r < 4; ++r) {
            int gr = row0 + wr * 64 + i * 16 + (lane >> 4) * 4 + r;
            int bb = gr >> 10, s = gr & 1023;
#pragma unroll
            for (int j = 0; j < 4; ++j) {
                int gc = col0 + wc * 64 + j * 16 + (lane & 15);
                int h = gc & 7, f = gc >> 3;
                f16 v = (f16)acc[i][j][r];
                if (mode == 0)
                    O[((size_t)(bb * 8 + h) * SQ + s) * FQ + f] = v;
                else
                    O[((size_t)(bb * 8 + h) * FQ + f) * SQ + s] = v;
            }
        }
}

// ---------------------------------------------------------------------------
// Kernel: P = sigmoid(16 * Q_bh @ K_bh^T). M=N=1024, K=256 per (b,h).
// ---------------------------------------------------------------------------
__global__ __launch_bounds__(256) void qk_mfma(const f16* __restrict__ Qb,
                                               const f16* __restrict__ Kb,
                                               f16* __restrict__ P, int bh0) {
    __shared__ f16 As[128 * LDSPAD];
    __shared__ f16 Bs[128 * LDSPAD];
    const int bh = bh0 + blockIdx.z;
    const f16* Aq = Qb + (size_t)bh * SQ * FQ;
    const f16* Bk = Kb + (size_t)bh * SQ * FQ;
    f16* Pz = P + (size_t)blockIdx.z * SQ * SQ;
    f32x4 acc[4][4] = {};
    const int row0 = blockIdx.y * 128, col0 = blockIdx.x * 128;
    gemm128(Aq, FQ, Bk, FQ, FQ, As, Bs, acc, row0, col0);

    const int lane = threadIdx.x & 63;
    const int w = threadIdx.x >> 6, wr = w >> 1, wc = w & 1;
#pragma unroll
    for (int i = 0; i < 4; ++i)
#pragma unroll
        for (int r = 0; r < 4; ++r) {
            int gr = row0 + wr * 64 + i * 16 + (lane >> 4) * 4 + r;
#pragma unroll
            for (int j = 0; j < 4; ++j) {
                int gc = col0 + wc * 64 + j * 16 + (lane & 15);
                float p = 1.0f / (1.0f + __expf(-16.0f * acc[i][j][r]));
                Pz[(size_t)gr * SQ + gc] = (f16)p;
            }
        }
}

// ---------------------------------------------------------------------------
// Kernel: WV = P @ V_bh. M=1024, N=256, K=1024. V in (b,h,f,s) = Bt layout.
// Output scattered to WV[(b*S+i)][f*8+h] f16.
// ---------------------------------------------------------------------------
__global__ __launch_bounds__(256) void pv_mfma(const f16* __restrict__ P,
                                               const f16* __restrict__ Vt,
                                               f16* __restrict__ WV, int bh0) {
    __shared__ f16 As[128 * LDSPAD];
    __shared__ f16 Bs[128 * LDSPAD];
    const int bh = bh0 + blockIdx.z;
    const int bb = bh >> 3, h = bh & 7;
    const f16* Ap = P + (size_t)blockIdx.z * SQ * SQ;
    const f16* Bv = Vt + (size_t)bh * FQ * SQ;
    f32x4 acc[4][4] = {};
    const int row0 = blockIdx.y * 128, col0 = blockIdx.x * 128;
    gemm128(Ap, SQ, Bv, SQ, SQ, As, Bs, acc, row0, col0);

    const int lane = threadIdx.x & 63;
    const int w = threadIdx.x >> 6, wr = w >> 1, wc = w & 1;
#pragma unroll
    for (int i = 0; i < 4; ++i)
#pragma unroll
        for (int r = 0; r < 4; ++r) {
            int gr = row0 + wr * 64 + i * 16 + (lane >> 4) * 4 + r;
#pragma unroll
            for (int j = 0; j < 4; ++j) {
                int f = col0 + wc * 64 + j * 16 + (lane & 15);
                WV[((size_t)(bb * SQ + gr)) * FH + f * 8 + h] = (f16)acc[i][j][r];
            }
        }
}

// ---------------------------------------------------------------------------
// Kernel: out = relu(WV(4096x2048) @ Wo) via WoT. M=4096, N=256, K=2048. fp32 out.
// ---------------------------------------------------------------------------
__global__ __launch_bounds__(256) void out_mfma(const f16* __restrict__ WV,
                                                const f16* __restrict__ WoT,
                                                float* __restrict__ O) {
    __shared__ f16 As[128 * LDSPAD];
    __shared__ f16 Bs[128 * LDSPAD];
    f32x4 acc[4][4] = {};
    const int row0 = blockIdx.y * 128, col0 = blockIdx.x * 128;
    gemm128(WV, FH, WoT, FH, FH, As, Bs, acc, row0, col0);

    const int lane = threadIdx.x & 63;
    const int w = threadIdx.x >> 6, wr = w >> 1, wc = w & 1;
#pragma unroll
    for (int i = 0; i < 4; ++i)
#pragma unroll
        for (int r = 0; r < 4; ++r) {
            int gr = row0 + wr * 64 + i * 16 + (lane >> 4) * 4 + r;
#pragma unroll
            for (int j = 0; j < 4; ++j) {
                int gc = col0 + wc * 64 + j * 16 + (lane & 15);
                O[(size_t)gr * FQ + gc] = fmaxf(acc[i][j][r], 0.0f);
            }
        }
}

// ---------------------------------------------------------------------------
extern "C" void kernel_launch(void* const* d_in, const int* in_sizes, int n_in,
                              void* d_out, int out_size, void* d_ws, size_t ws_size,
                              hipStream_t stream) {
    const float* x  = (const float*)d_in[0];
    const float* Wq = (const float*)d_in[1];
    const float* Wk = (const float*)d_in[2];
    const float* Wv = (const float*)d_in[3];
    const float* Wo = (const float*)d_in[4];
    float* out = (float*)d_out;

    f16* ws = (f16*)d_ws;
    f16* xh   = ws;                       // 1,048,576
    f16* wqT  = xh   + 1048576;           // 524,288 (2048 x 256)
    f16* wkT  = wqT  + 524288;
    f16* wvT  = wkT  + 524288;
    f16* woT  = wvT  + 524288;            // 524,288 (256 x 2048)
    f16* qbuf = woT  + 524288;            // 8,388,608 (b,h,s,f)
    f16* kbuf = qbuf + 8388608;
    f16* vbuf = kbuf + 8388608;           // (b,h,f,s)
    f16* wvbuf= vbuf + 8388608;           // (b*s, f*8+h)
    f16* pbuf = wvbuf+ 8388608;           // chunk * 1,048,576

    const size_t baseB = (size_t)(36700160) * 2;       // everything before pbuf
    const size_t pbhB  = (size_t)SQ * SQ * 2;          // 2 MiB per (b,h)
    int chunk = 1;
    if      (ws_size >= baseB + 32 * pbhB) chunk = 32;
    else if (ws_size >= baseB + 16 * pbhB) chunk = 16;
    else if (ws_size >= baseB +  8 * pbhB) chunk = 8;
    else if (ws_size >= baseB +  4 * pbhB) chunk = 4;
    else if (ws_size >= baseB +  2 * pbhB) chunk = 2;

    dim3 blk(256);
    cvt_kernel<<<dim3(1024), blk, 0, stream>>>(x, xh);
    transpose_kernel<<<dim3(64, 8), blk, 0, stream>>>(Wq, wqT, FQ, FH);
    transpose_kernel<<<dim3(64, 8), blk, 0, stream>>>(Wk, wkT, FQ, FH);
    transpose_kernel<<<dim3(64, 8), blk, 0, stream>>>(Wv, wvT, FQ, FH);
    transpose_kernel<<<dim3(8, 64), blk, 0, stream>>>(Wo, woT, FH, FQ);

    proj_mfma<<<dim3(16, 32), blk, 0, stream>>>(xh, wqT, qbuf, 0);
    proj_mfma<<<dim3(16, 32), blk, 0, stream>>>(xh, wkT, kbuf, 0);
    proj_mfma<<<dim3(16, 32), blk, 0, stream>>>(xh, wvT, vbuf, 1);

    for (int bh0 = 0; bh0 < 32; bh0 += chunk) {
        qk_mfma<<<dim3(8, 8, chunk), blk, 0, stream>>>(qbuf, kbuf, pbuf, bh0);
        pv_mfma<<<dim3(2, 8, chunk), blk, 0, stream>>>(pbuf, vbuf, wvbuf, bh0);
    }
    out_mfma<<<dim3(2, 32), blk, 0, stream>>>(wvbuf, woT, out);
}

// Round 3
// 268.582 us; speedup vs baseline: 3.1126x; 1.0973x over previous
//
#include <hip/hip_runtime.h>
#include <math.h>

// Problem: B=4, S=1024, F=256, H=8, FH=2048. SCALE=16 (multiplies logits).
#define SQ 1024
#define FQ 256
#define FH 2048

typedef _Float16 f16;
typedef f16  f16x8 __attribute__((ext_vector_type(8)));
typedef float f32x4 __attribute__((ext_vector_type(4)));

// Async global->LDS, 16 B per lane. LDS dest = wave-uniform base + lane*16.
#define GLOAD_LDS16(gp, lp) \
    __builtin_amdgcn_global_load_lds((const __attribute__((address_space(1))) void*)(gp), \
                                     (__attribute__((address_space(3))) void*)(lp), 16, 0, 0)

// ---------------------------------------------------------------------------
// fp32 -> f16 convert (x input).
// ---------------------------------------------------------------------------
__global__ __launch_bounds__(256) void cvt_kernel(const float* __restrict__ in,
                                                  f16* __restrict__ out) {
    int idx = (blockIdx.x * 256 + threadIdx.x) * 4;
    float4 v = *(const float4*)(in + idx);
    out[idx + 0] = (f16)v.x; out[idx + 1] = (f16)v.y;
    out[idx + 2] = (f16)v.z; out[idx + 3] = (f16)v.w;
}

// ---------------------------------------------------------------------------
// Transpose + convert: W (K x N fp32) -> WT (N x K f16).
// ---------------------------------------------------------------------------
__global__ __launch_bounds__(256) void transpose_kernel(const float* __restrict__ W,
                                                        f16* __restrict__ WT,
                                                        int K, int N) {
    __shared__ f16 T[32][33];
    const int tx = threadIdx.x & 31, ty = threadIdx.x >> 5;
    const int n0 = blockIdx.x * 32, k0 = blockIdx.y * 32;
#pragma unroll
    for (int i = 0; i < 4; ++i)
        T[ty + i * 8][tx] = (f16)W[(size_t)(k0 + ty + i * 8) * N + n0 + tx];
    __syncthreads();
#pragma unroll
    for (int i = 0; i < 4; ++i)
        WT[(size_t)(n0 + ty + i * 8) * K + k0 + tx] = T[tx][ty + i * 8];
}

// ---------------------------------------------------------------------------
// Stage (nregions*16) rows x 32 f16 (row-major, stride 32) from
// G[row0 + r][k0 + c] into S via global_load_lds. 1 region = 16 rows = 1 KiB.
// ---------------------------------------------------------------------------
__device__ __forceinline__ void stage_rows32(const f16* __restrict__ G, int ldg,
                                             int row0, int k0, f16* S,
                                             int nregions, int w, int lane) {
#pragma unroll
    for (int rI = w; rI < nregions; rI += 4) {
        int r = rI * 16 + (lane >> 2);
        int col = (lane & 3) << 3;
        GLOAD_LDS16(G + (size_t)(row0 + r) * ldg + k0 + col, S + rI * 512);
    }
}

// ---------------------------------------------------------------------------
// 128x128 MFMA tile, BK=32, m97-style global_load_lds staging.
// A: [M][K] row-major; Bt: [N][K] row-major. 4 waves in 2x2 of 64x64.
// ---------------------------------------------------------------------------
__device__ __forceinline__ void gemm128_lds(const f16* __restrict__ A, int lda,
                                            const f16* __restrict__ Bt, int ldb,
                                            int K, f16* As, f16* Bs,
                                            f32x4 acc[4][4], int row0, int col0) {
    const int t = threadIdx.x, lane = t & 63, w = t >> 6;
    const int wr = w >> 1, wc = w & 1;
    const int lrow = lane & 15, quad = lane >> 4;
    for (int k0 = 0; k0 < K; k0 += 32) {
        __syncthreads();
        stage_rows32(A, lda, row0, k0, As, 8, w, lane);
        stage_rows32(Bt, ldb, col0, k0, Bs, 8, w, lane);
        __syncthreads();
        f16x8 af[4], bf[4];
#pragma unroll
        for (int i = 0; i < 4; ++i) {
            af[i] = *(const f16x8*)&As[(wr * 64 + i * 16 + lrow) * 32 + quad * 8];
            bf[i] = *(const f16x8*)&Bs[(wc * 64 + i * 16 + lrow) * 32 + quad * 8];
        }
#pragma unroll
        for (int i = 0; i < 4; ++i)
#pragma unroll
            for (int j = 0; j < 4; ++j)
                acc[i][j] = __builtin_amdgcn_mfma_f32_16x16x32_f16(af[i], bf[j], acc[i][j], 0, 0, 0);
    }
}

// ---------------------------------------------------------------------------
// QKV projection: C(4096x2048) = xh @ W (via WT).
// mode 0: scatter to (b,h,s,f). mode 1 (V): scatter to (b,h,f,s).
// ---------------------------------------------------------------------------
__global__ __launch_bounds__(256) void proj_mfma(const f16* __restrict__ xh,
                                                 const f16* __restrict__ WT,
                                                 f16* __restrict__ O, int mode) {
    __shared__ f16 As[128 * 32];
    __shared__ f16 Bs[128 * 32];
    f32x4 acc[4][4] = {};
    const int row0 = blockIdx.y * 128, col0 = blockIdx.x * 128;
    gemm128_lds(xh, FQ, WT, FQ, FQ, As, Bs, acc, row0, col0);

    const int lane = threadIdx.x & 63;
    const int w = threadIdx.x >> 6, wr = w >> 1, wc = w & 1;
#pragma unroll
    for (int i = 0; i < 4; ++i)
#pragma unroll
        for (int r = 0; r < 4; ++r) {
            int gr = row0 + wr * 64 + i * 16 + (lane >> 4) * 4 + r;
            int bb = gr >> 10, s = gr & 1023;
#pragma unroll
            for (int j = 0; j < 4; ++j) {
                int gc = col0 + wc * 64 + j * 16 + (lane & 15);
                int h = gc & 7, f = gc >> 3;
                f16 v = (f16)acc[i][j][r];
                if (mode == 0)
                    O[((size_t)(bb * 8 + h) * SQ + s) * FQ + f] = v;
                else
                    O[((size_t)(bb * 8 + h) * FQ + f) * SQ + s] = v;
            }
        }
}

// ---------------------------------------------------------------------------
// Fused attention: per (b,h), 64-row Q strip. For each of 8 column tiles j:
//   S = Q_strip @ K_j^T (K=256) -> sigmoid -> Ps (LDS, swizzled) -> WV += Ps @ V_j^T.
// P never touches HBM. LDS: Qs 32 KiB + Ps 16 KiB + KVs 16 KiB = 64 KiB.
// Swizzle: granule g' = g ^ (row & 7) makes frag reads 2-way (free).
// ---------------------------------------------------------------------------
__global__ __launch_bounds__(256, 2) void fused_attn(const f16* __restrict__ Qb,
                                                     const f16* __restrict__ Kb,
                                                     const f16* __restrict__ Vt,
                                                     f16* __restrict__ WV) {
    __shared__ f16 Qs[64 * 256];
    __shared__ f16 Ps[64 * 128];
    __shared__ f16 KVs[256 * 32];
    const int t = threadIdx.x, lane = t & 63, w = t >> 6;
    const int lrow = lane & 15, quad = lane >> 4;
    // XCD-aware swizzle: each XCD works on 4 consecutive heads for L2 locality.
    const int n = blockIdx.y * gridDim.x + blockIdx.x;   // 0..511
    const int xcd = n & 7, rest = n >> 3;
    const int bh = xcd * 4 + (rest & 3);
    const int strip = rest >> 2;                         // 0..15
    const int m0 = strip * 64;
    const int bb = bh >> 3, h = bh & 7;
    const f16* Qg = Qb + (size_t)bh * SQ * FQ;
    const f16* Kg = Kb + (size_t)bh * SQ * FQ;
    const f16* Vg = Vt + (size_t)bh * FQ * SQ;

    // Stage Q strip (64x256) once, granule-swizzled.
#pragma unroll
    for (int it = 0; it < 8; ++it) {
        int c = t + it * 256;
        int r = c >> 5, g = c & 31;
        float4 v = *(const float4*)(Qg + (size_t)(m0 + r) * FQ + (g << 3));
        *(float4*)&Qs[r * 256 + (((g ^ (r & 7)) & 31) << 3)] = v;
    }

    f32x4 acc_o[4][4] = {};   // WV accumulator: 64 rows x 256 f, wave w owns f[64w..64w+63]

    for (int j0 = 0; j0 < SQ; j0 += 128) {
        // ---- QK^T: S(64x128) over K=256; wave w owns S cols [32w, 32w+32) ----
        f32x4 acc_s[4][2] = {};
        for (int k0 = 0; k0 < FQ; k0 += 32) {
            __syncthreads();
            stage_rows32(Kg, FQ, j0, k0, KVs, 8, w, lane);
            __syncthreads();
            f16x8 af[4], bf[2];
#pragma unroll
            for (int m = 0; m < 4; ++m) {
                int r = m * 16 + lrow;
                int g = (k0 >> 3) + quad;
                af[m] = *(const f16x8*)&Qs[r * 256 + (((g ^ (r & 7)) & 31) << 3)];
            }
#pragma unroll
            for (int nn = 0; nn < 2; ++nn)
                bf[nn] = *(const f16x8*)&KVs[(w * 32 + nn * 16 + lrow) * 32 + quad * 8];
#pragma unroll
            for (int m = 0; m < 4; ++m)
#pragma unroll
                for (int nn = 0; nn < 2; ++nn)
                    acc_s[m][nn] = __builtin_amdgcn_mfma_f32_16x16x32_f16(af[m], bf[nn], acc_s[m][nn], 0, 0, 0);
        }
        // ---- sigmoid -> Ps (C/D layout: row = quad*4+reg, col = lane&15) ----
#pragma unroll
        for (int m = 0; m < 4; ++m)
#pragma unroll
            for (int nn = 0; nn < 2; ++nn)
#pragma unroll
                for (int r = 0; r < 4; ++r) {
                    int prow = m * 16 + quad * 4 + r;
                    int col = w * 32 + nn * 16 + lrow;
                    int g = col >> 3;
                    float p = 1.0f / (1.0f + __expf(-16.0f * acc_s[m][nn][r]));
                    Ps[prow * 128 + (((g ^ (prow & 7)) & 15) << 3) + (col & 7)] = (f16)p;
                }
        // ---- PV: WV(64x256) += Ps(64x128) @ V_j^T; wave w owns f [64w,64w+64) ----
        for (int kc = 0; kc < 128; kc += 32) {
            __syncthreads();   // Ps visible; KVs free for V
            stage_rows32(Vg, SQ, 0, j0 + kc, KVs, 16, w, lane);
            __syncthreads();
            f16x8 ap[4], bv[4];
#pragma unroll
            for (int m = 0; m < 4; ++m) {
                int r = m * 16 + lrow;
                int g = (kc >> 3) + quad;
                ap[m] = *(const f16x8*)&Ps[r * 128 + (((g ^ (r & 7)) & 15) << 3)];
            }
#pragma unroll
            for (int nn = 0; nn < 4; ++nn)
                bv[nn] = *(const f16x8*)&KVs[(w * 64 + nn * 16 + lrow) * 32 + quad * 8];
#pragma unroll
            for (int m = 0; m < 4; ++m)
#pragma unroll
                for (int nn = 0; nn < 4; ++nn)
                    acc_o[m][nn] = __builtin_amdgcn_mfma_f32_16x16x32_f16(ap[m], bv[nn], acc_o[m][nn], 0, 0, 0);
        }
    }
    // ---- epilogue: scatter WV to (row = b*S + s, col = f*8 + h) f16 ----
#pragma unroll
    for (int m = 0; m < 4; ++m)
#pragma unroll
        for (int r = 0; r < 4; ++r) {
            int gr = m0 + m * 16 + quad * 4 + r;
#pragma unroll
            for (int nn = 0; nn < 4; ++nn) {
                int f = w * 64 + nn * 16 + lrow;
                WV[((size_t)(bb * SQ + gr)) * FH + f * 8 + h] = (f16)acc_o[m][nn][r];
            }
        }
}

// ---------------------------------------------------------------------------
// out = relu(WV(4096x2048) @ Wo) via WoT. fp32 out.
// ---------------------------------------------------------------------------
__global__ __launch_bounds__(256) void out_mfma(const f16* __restrict__ WV,
                                                const f16* __restrict__ WoT,
                                                float* __restrict__ O) {
    __shared__ f16 As[128 * 32];
    __shared__ f16 Bs[128 * 32];
    f32x4 acc[4][4] = {};
    const int row0 = blockIdx.y * 128, col0 = blockIdx.x * 128;
    gemm128_lds(WV, FH, WoT, FH, FH, As, Bs, acc, row0, col0);

    const int lane = threadIdx.x & 63;
    const int w = threadIdx.x >> 6, wr = w >> 1, wc = w & 1;
#pragma unroll
    for (int i = 0; i < 4; ++i)
#pragma unroll
        for (int r = 0; r < 4; ++r) {
            int gr = row0 + wr * 64 + i * 16 + (lane >> 4) * 4 + r;
#pragma unroll
            for (int j = 0; j < 4; ++j) {
                int gc = col0 + wc * 64 + j * 16 + (lane & 15);
                O[(size_t)gr * FQ + gc] = fmaxf(acc[i][j][r], 0.0f);
            }
        }
}

// ---------------------------------------------------------------------------
extern "C" void kernel_launch(void* const* d_in, const int* in_sizes, int n_in,
                              void* d_out, int out_size, void* d_ws, size_t ws_size,
                              hipStream_t stream) {
    const float* x  = (const float*)d_in[0];
    const float* Wq = (const float*)d_in[1];
    const float* Wk = (const float*)d_in[2];
    const float* Wv = (const float*)d_in[3];
    const float* Wo = (const float*)d_in[4];
    float* out = (float*)d_out;

    f16* ws = (f16*)d_ws;
    f16* xh    = ws;                       // 1,048,576
    f16* wqT   = xh    + 1048576;          // 524,288 (2048 x 256)
    f16* wkT   = wqT   + 524288;
    f16* wvT   = wkT   + 524288;
    f16* woT   = wvT   + 524288;           // 524,288 (256 x 2048)
    f16* qbuf  = woT   + 524288;           // 8,388,608 (b,h,s,f)
    f16* kbuf  = qbuf  + 8388608;          // (b,h,s,f)
    f16* vbuf  = kbuf  + 8388608;          // (b,h,f,s)
    f16* wvbuf = vbuf  + 8388608;          // (b*s, f*8+h)

    dim3 blk(256);
    cvt_kernel<<<dim3(1024), blk, 0, stream>>>(x, xh);
    transpose_kernel<<<dim3(64, 8), blk, 0, stream>>>(Wq, wqT, FQ, FH);
    transpose_kernel<<<dim3(64, 8), blk, 0, stream>>>(Wk, wkT, FQ, FH);
    transpose_kernel<<<dim3(64, 8), blk, 0, stream>>>(Wv, wvT, FQ, FH);
    transpose_kernel<<<dim3(8, 64), blk, 0, stream>>>(Wo, woT, FH, FQ);

    proj_mfma<<<dim3(16, 32), blk, 0, stream>>>(xh, wqT, qbuf, 0);
    proj_mfma<<<dim3(16, 32), blk, 0, stream>>>(xh, wkT, kbuf, 0);
    proj_mfma<<<dim3(16, 32), blk, 0, stream>>>(xh, wvT, vbuf, 1);

    fused_attn<<<dim3(16, 32), blk, 0, stream>>>(qbuf, kbuf, vbuf, wvbuf);

    out_mfma<<<dim3(2, 32), blk, 0, stream>>>(wvbuf, woT, out);
}

// Round 4
// 263.851 us; speedup vs baseline: 3.1684x; 1.0179x over previous
//
#include <hip/hip_runtime.h>
#include <math.h>

// Problem: B=4, S=1024, F=256, H=8, FH=2048. SCALE=16 (multiplies logits).
#define SQ 1024
#define FQ 256
#define FH 2048

typedef _Float16 f16;
typedef f16  f16x8 __attribute__((ext_vector_type(8)));
typedef float f32x4 __attribute__((ext_vector_type(4)));

// Async global->LDS, 16 B/lane. LDS dest = wave-uniform base + lane*16.
#define GLOAD_LDS16(gp, lp) \
    __builtin_amdgcn_global_load_lds((const __attribute__((address_space(1))) void*)(gp), \
                                     (__attribute__((address_space(3))) void*)(lp), 16, 0, 0)

// ---------------------------------------------------------------------------
// fp32 -> f16 convert (x input).
// ---------------------------------------------------------------------------
__global__ __launch_bounds__(256) void cvt_kernel(const float* __restrict__ in,
                                                  f16* __restrict__ out) {
    int idx = (blockIdx.x * 256 + threadIdx.x) * 4;
    float4 v = *(const float4*)(in + idx);
    out[idx + 0] = (f16)v.x; out[idx + 1] = (f16)v.y;
    out[idx + 2] = (f16)v.z; out[idx + 3] = (f16)v.w;
}

// ---------------------------------------------------------------------------
// Transpose+convert W (256 x 2048 fp32) -> WT (2048 x 256 f16). z picks matrix.
// ---------------------------------------------------------------------------
__global__ __launch_bounds__(256) void transpose_qkv(const float* __restrict__ W0,
                                                     const float* __restrict__ W1,
                                                     const float* __restrict__ W2,
                                                     f16* __restrict__ T0,
                                                     f16* __restrict__ T1,
                                                     f16* __restrict__ T2) {
    const float* W = blockIdx.z == 0 ? W0 : (blockIdx.z == 1 ? W1 : W2);
    f16* WT        = blockIdx.z == 0 ? T0 : (blockIdx.z == 1 ? T1 : T2);
    __shared__ f16 T[32][33];
    const int tx = threadIdx.x & 31, ty = threadIdx.x >> 5;
    const int n0 = blockIdx.x * 32, k0 = blockIdx.y * 32;
#pragma unroll
    for (int i = 0; i < 4; ++i)
        T[ty + i * 8][tx] = (f16)W[(size_t)(k0 + ty + i * 8) * FH + n0 + tx];
    __syncthreads();
#pragma unroll
    for (int i = 0; i < 4; ++i)
        WT[(size_t)(n0 + ty + i * 8) * FQ + k0 + tx] = T[tx][ty + i * 8];
}

__global__ __launch_bounds__(256) void transpose_wo(const float* __restrict__ W,
                                                    f16* __restrict__ WT) {
    __shared__ f16 T[32][33];
    const int tx = threadIdx.x & 31, ty = threadIdx.x >> 5;
    const int n0 = blockIdx.x * 32, k0 = blockIdx.y * 32;
#pragma unroll
    for (int i = 0; i < 4; ++i)
        T[ty + i * 8][tx] = (f16)W[(size_t)(k0 + ty + i * 8) * FQ + n0 + tx];
    __syncthreads();
#pragma unroll
    for (int i = 0; i < 4; ++i)
        WT[(size_t)(n0 + ty + i * 8) * FH + k0 + tx] = T[tx][ty + i * 8];
}

// ---------------------------------------------------------------------------
// m97-style staging: (nregions*16) rows x 32 f16, row stride 32, unswizzled.
// ---------------------------------------------------------------------------
__device__ __forceinline__ void stage_rows32(const f16* __restrict__ G, int ldg,
                                             int row0, int k0, f16* S,
                                             int nregions, int w, int lane) {
#pragma unroll
    for (int rI = w; rI < nregions; rI += 4) {
        int r = rI * 16 + (lane >> 2);
        int col = (lane & 3) << 3;
        GLOAD_LDS16(G + (size_t)(row0 + r) * ldg + k0 + col, S + rI * 512);
    }
}

// ---------------------------------------------------------------------------
// Swizzled BK=64 staging: nrows x 64 f16 tile, LDS row stride 64 f16 (128 B),
// logical granule g stored at physical g^(row&7). 1 inst = 8 rows (1 KiB).
// Read addr for [row][granule g]: row*64 + ((g ^ (row&7)) << 3).
// ---------------------------------------------------------------------------
__device__ __forceinline__ void stage_sw64(const f16* __restrict__ G, int ldg,
                                           int row0, int c0, f16* S,
                                           int nrows, int w, int lane) {
    const int rsub = lane >> 3;                       // 0..7 row within region
    const int g    = (lane & 7) ^ (rsub & 7);         // source granule
#pragma unroll
    for (int rg = w; rg < (nrows >> 3); rg += 4) {
        GLOAD_LDS16(G + (size_t)(row0 + rg * 8 + rsub) * ldg + c0 + g * 8,
                    S + rg * 512);
    }
}

// ---------------------------------------------------------------------------
// 128x128 MFMA tile, BK=32 (proj). 4 waves 2x2 of 64x64.
// ---------------------------------------------------------------------------
__device__ __forceinline__ void gemm128_lds(const f16* __restrict__ A, int lda,
                                            const f16* __restrict__ Bt, int ldb,
                                            int K, f16* As, f16* Bs,
                                            f32x4 acc[4][4], int row0, int col0) {
    const int t = threadIdx.x, lane = t & 63, w = t >> 6;
    const int wr = w >> 1, wc = w & 1;
    const int lrow = lane & 15, quad = lane >> 4;
    for (int k0 = 0; k0 < K; k0 += 32) {
        __syncthreads();
        stage_rows32(A, lda, row0, k0, As, 8, w, lane);
        stage_rows32(Bt, ldb, col0, k0, Bs, 8, w, lane);
        __syncthreads();
        f16x8 af[4], bf[4];
#pragma unroll
        for (int i = 0; i < 4; ++i) {
            af[i] = *(const f16x8*)&As[(wr * 64 + i * 16 + lrow) * 32 + quad * 8];
            bf[i] = *(const f16x8*)&Bs[(wc * 64 + i * 16 + lrow) * 32 + quad * 8];
        }
#pragma unroll
        for (int i = 0; i < 4; ++i)
#pragma unroll
            for (int j = 0; j < 4; ++j)
                acc[i][j] = __builtin_amdgcn_mfma_f32_16x16x32_f16(af[i], bf[j], acc[i][j], 0, 0, 0);
    }
}

// ---------------------------------------------------------------------------
// Merged QKV projection: z=0 Q (b,h,s,f), z=1 K (b,h,s,f), z=2 V (b,h,f,s).
// ---------------------------------------------------------------------------
__global__ __launch_bounds__(256) void proj_mfma(const f16* __restrict__ xh,
                                                 const f16* __restrict__ wqT,
                                                 const f16* __restrict__ wkT,
                                                 const f16* __restrict__ wvT,
                                                 f16* __restrict__ qb,
                                                 f16* __restrict__ kb,
                                                 f16* __restrict__ vb) {
    const int z = blockIdx.z;
    const f16* WT = z == 0 ? wqT : (z == 1 ? wkT : wvT);
    f16* O        = z == 0 ? qb  : (z == 1 ? kb  : vb);
    __shared__ f16 As[128 * 32];
    __shared__ f16 Bs[128 * 32];
    f32x4 acc[4][4] = {};
    const int row0 = blockIdx.y * 128, col0 = blockIdx.x * 128;
    gemm128_lds(xh, FQ, WT, FQ, FQ, As, Bs, acc, row0, col0);

    const int lane = threadIdx.x & 63;
    const int w = threadIdx.x >> 6, wr = w >> 1, wc = w & 1;
#pragma unroll
    for (int i = 0; i < 4; ++i)
#pragma unroll
        for (int r = 0; r < 4; ++r) {
            int gr = row0 + wr * 64 + i * 16 + (lane >> 4) * 4 + r;
            int bb = gr >> 10, s = gr & 1023;
#pragma unroll
            for (int j = 0; j < 4; ++j) {
                int gc = col0 + wc * 64 + j * 16 + (lane & 15);
                int h = gc & 7, f = gc >> 3;
                f16 v = (f16)acc[i][j][r];
                if (z != 2) O[((size_t)(bb * 8 + h) * SQ + s) * FQ + f] = v;
                else        O[((size_t)(bb * 8 + h) * FQ + f) * SQ + s] = v;
            }
        }
}

// ---------------------------------------------------------------------------
// Fused attention v2. Per block: 64 Q-rows of one (b,h).
//  - Q as register A-fragments (loaded once).
//  - j0 loop over 8 tiles of 128 K-cols: QK^T (BK=64, 4 stage-pairs)
//    -> sigmoid -> Ps (LDS, stride 136) -> PV (BK=64, 2 stage-pairs).
//  - 12 barriers/j0. LDS: Ps 17 KiB + KVs 32 KiB = 49.4 KiB.
// Waves 2x2: wr = row half (32 rows), wc = col half.
// ---------------------------------------------------------------------------
__global__ __launch_bounds__(256) void fused_attn(const f16* __restrict__ Qb,
                                                  const f16* __restrict__ Kb,
                                                  const f16* __restrict__ Vt,
                                                  f16* __restrict__ WV) {
    __shared__ f16 Ps[64 * 136];
    __shared__ f16 KVs[256 * 64];
    const int t = threadIdx.x, lane = t & 63, w = t >> 6;
    const int wr = w >> 1, wc = w & 1;
    const int lrow = lane & 15, quad = lane >> 4;
    // XCD swizzle: 4 consecutive heads per XCD for K/V L2 locality.
    const int n = blockIdx.x;
    const int xcd = n & 7, rest = n >> 3;
    const int bh = xcd * 4 + (rest & 3);
    const int strip = rest >> 2;          // 0..15
    const int m0 = strip * 64;
    const int bb = bh >> 3, h = bh & 7;
    const f16* Qg = Qb + (size_t)bh * SQ * FQ;
    const f16* Kg = Kb + (size_t)bh * SQ * FQ;
    const f16* Vg = Vt + (size_t)bh * FQ * SQ;

    // Q as A-fragments in registers: qf[mi][kf], rows 32wr+16mi+lrow, k=kf*32+quad*8.
    f16x8 qf[2][8];
#pragma unroll
    for (int mi = 0; mi < 2; ++mi)
#pragma unroll
        for (int kf = 0; kf < 8; ++kf)
            qf[mi][kf] = *(const f16x8*)(Qg + (size_t)(m0 + 32 * wr + 16 * mi + lrow) * FQ
                                             + kf * 32 + quad * 8);

    f32x4 acc_o[2][8] = {};   // WV rows 32wr+16mi(+quad*4+r), f cols 128wc+16nj+lrow

    for (int j0 = 0; j0 < SQ; j0 += 128) {
        // ---- QK^T: S(64x128); wave computes rows 32wr..+32, cols 64wc..+64 ----
        f32x4 acc_s[2][4] = {};
#pragma unroll
        for (int ks = 0; ks < 4; ++ks) {            // K feature dim, BK=64
            __syncthreads();                        // KVs free (prev reads done)
            stage_sw64(Kg, FQ, j0, ks * 64, KVs, 128, w, lane);
            __syncthreads();
            f16x8 bf[4][2];
#pragma unroll
            for (int nj = 0; nj < 4; ++nj) {
                int row = 64 * wc + 16 * nj + lrow;
#pragma unroll
                for (int kf = 0; kf < 2; ++kf)
                    bf[nj][kf] = *(const f16x8*)&KVs[row * 64 + (((kf * 4 + quad) ^ (row & 7)) << 3)];
            }
#pragma unroll
            for (int mi = 0; mi < 2; ++mi)
#pragma unroll
                for (int nj = 0; nj < 4; ++nj)
#pragma unroll
                    for (int kf = 0; kf < 2; ++kf)
                        acc_s[mi][nj] = __builtin_amdgcn_mfma_f32_16x16x32_f16(
                            qf[mi][ks * 2 + kf], bf[nj][kf], acc_s[mi][nj], 0, 0, 0);
        }
        // ---- sigmoid -> Ps (stride 136: quad-rows 2-way free) ----
#pragma unroll
        for (int mi = 0; mi < 2; ++mi)
#pragma unroll
            for (int nj = 0; nj < 4; ++nj)
#pragma unroll
                for (int rr = 0; rr < 4; ++rr) {
                    int prow = 32 * wr + 16 * mi + 4 * quad + rr;
                    int col  = 64 * wc + 16 * nj + lrow;
                    float p = 1.0f / (1.0f + __expf(-16.0f * acc_s[mi][nj][rr]));
                    Ps[prow * 136 + col] = (f16)p;
                }
        // ---- PV: WV(64x256) += Ps(64x128) @ V^T; BK=64 over the 128 cols ----
#pragma unroll
        for (int kc = 0; kc < 2; ++kc) {
            __syncthreads();                        // Ps visible / KVs reads done
            stage_sw64(Vg, SQ, 0, j0 + kc * 64, KVs, 256, w, lane);
            __syncthreads();
            f16x8 ap[2][2], bv[8][2];
#pragma unroll
            for (int mi = 0; mi < 2; ++mi)
#pragma unroll
                for (int kf = 0; kf < 2; ++kf)
                    ap[mi][kf] = *(const f16x8*)&Ps[(32 * wr + 16 * mi + lrow) * 136
                                                    + kc * 64 + kf * 32 + quad * 8];
#pragma unroll
            for (int nj = 0; nj < 8; ++nj) {
                int row = 128 * wc + 16 * nj + lrow;   // f index
#pragma unroll
                for (int kf = 0; kf < 2; ++kf)
                    bv[nj][kf] = *(const f16x8*)&KVs[row * 64 + (((kf * 4 + quad) ^ (row & 7)) << 3)];
            }
#pragma unroll
            for (int mi = 0; mi < 2; ++mi)
#pragma unroll
                for (int nj = 0; nj < 8; ++nj)
#pragma unroll
                    for (int kf = 0; kf < 2; ++kf)
                        acc_o[mi][nj] = __builtin_amdgcn_mfma_f32_16x16x32_f16(
                            ap[mi][kf], bv[nj][kf], acc_o[mi][nj], 0, 0, 0);
        }
    }
    // ---- epilogue: WV[(b*S + s)][f*8 + h] f16 ----
#pragma unroll
    for (int mi = 0; mi < 2; ++mi)
#pragma unroll
        for (int rr = 0; rr < 4; ++rr) {
            int gr = m0 + 32 * wr + 16 * mi + 4 * quad + rr;
#pragma unroll
            for (int nj = 0; nj < 8; ++nj) {
                int f = 128 * wc + 16 * nj + lrow;
                WV[((size_t)(bb * SQ + gr)) * FH + f * 8 + h] = (f16)acc_o[mi][nj][rr];
            }
        }
}

// ---------------------------------------------------------------------------
// out projection, split-K x2: partial[z] = WV[:, z*1024:(z+1)*1024] @ WoT^T.
// 64x64 tiles, grid (4, 64, 2). Waves 2x2 over 32x32.
// ---------------------------------------------------------------------------
__global__ __launch_bounds__(256) void out_split(const f16* __restrict__ WVm,
                                                 const f16* __restrict__ WoT,
                                                 float* __restrict__ PP) {
    __shared__ f16 As[64 * 32];
    __shared__ f16 Bs[64 * 32];
    const int t = threadIdx.x, lane = t & 63, w = t >> 6;
    const int wr = w >> 1, wc = w & 1;
    const int lrow = lane & 15, quad = lane >> 4;
    const int row0 = blockIdx.y * 64, col0 = blockIdx.x * 64;
    const int kbase = blockIdx.z * 1024;
    f32x4 acc[2][2] = {};
    for (int k0 = 0; k0 < 1024; k0 += 32) {
        __syncthreads();
        stage_rows32(WVm, FH, row0, kbase + k0, As, 4, w, lane);
        stage_rows32(WoT, FH, col0, kbase + k0, Bs, 4, w, lane);
        __syncthreads();
        f16x8 af[2], bf[2];
#pragma unroll
        for (int i = 0; i < 2; ++i) {
            af[i] = *(const f16x8*)&As[(wr * 32 + i * 16 + lrow) * 32 + quad * 8];
            bf[i] = *(const f16x8*)&Bs[(wc * 32 + i * 16 + lrow) * 32 + quad * 8];
        }
#pragma unroll
        for (int i = 0; i < 2; ++i)
#pragma unroll
            for (int j = 0; j < 2; ++j)
                acc[i][j] = __builtin_amdgcn_mfma_f32_16x16x32_f16(af[i], bf[j], acc[i][j], 0, 0, 0);
    }
    float* P = PP + (size_t)blockIdx.z * SQ * 4 * FQ;
#pragma unroll
    for (int i = 0; i < 2; ++i)
#pragma unroll
        for (int r = 0; r < 4; ++r) {
            int gr = row0 + wr * 32 + i * 16 + quad * 4 + r;
#pragma unroll
            for (int j = 0; j < 2; ++j) {
                int gc = col0 + wc * 32 + j * 16 + lrow;
                P[(size_t)gr * FQ + gc] = acc[i][j][r];
            }
        }
}

__global__ __launch_bounds__(256) void reduce_relu(const float* __restrict__ PP,
                                                   float* __restrict__ O) {
    int idx = (blockIdx.x * 256 + threadIdx.x) * 4;
    f32x4 a = *(const f32x4*)(PP + idx);
    f32x4 b = *(const f32x4*)(PP + 1048576 + idx);
    f32x4 s = a + b;
    f32x4 r = {fmaxf(s.x, 0.f), fmaxf(s.y, 0.f), fmaxf(s.z, 0.f), fmaxf(s.w, 0.f)};
    *(f32x4*)(O + idx) = r;
}

// ---------------------------------------------------------------------------
extern "C" void kernel_launch(void* const* d_in, const int* in_sizes, int n_in,
                              void* d_out, int out_size, void* d_ws, size_t ws_size,
                              hipStream_t stream) {
    const float* x  = (const float*)d_in[0];
    const float* Wq = (const float*)d_in[1];
    const float* Wk = (const float*)d_in[2];
    const float* Wv = (const float*)d_in[3];
    const float* Wo = (const float*)d_in[4];
    float* out = (float*)d_out;

    f16* ws = (f16*)d_ws;
    f16* xh    = ws;                       // 1,048,576
    f16* wqT   = xh    + 1048576;          // 524,288
    f16* wkT   = wqT   + 524288;
    f16* wvT   = wkT   + 524288;
    f16* woT   = wvT   + 524288;
    f16* qbuf  = woT   + 524288;           // 8,388,608 (b,h,s,f)
    f16* kbuf  = qbuf  + 8388608;          // (b,h,s,f)
    f16* vbuf  = kbuf  + 8388608;          // (b,h,f,s)
    f16* wvbuf = vbuf  + 8388608;          // (b*s, f*8+h)
    float* pp  = (float*)(wvbuf + 8388608);// 2 x 1,048,576 fp32 partials

    dim3 blk(256);
    cvt_kernel<<<dim3(1024), blk, 0, stream>>>(x, xh);
    transpose_qkv<<<dim3(64, 8, 3), blk, 0, stream>>>(Wq, Wk, Wv, wqT, wkT, wvT);
    transpose_wo<<<dim3(8, 64), blk, 0, stream>>>(Wo, woT);

    proj_mfma<<<dim3(16, 32, 3), blk, 0, stream>>>(xh, wqT, wkT, wvT, qbuf, kbuf, vbuf);

    fused_attn<<<dim3(512), blk, 0, stream>>>(qbuf, kbuf, vbuf, wvbuf);

    out_split<<<dim3(4, 64, 2), blk, 0, stream>>>(wvbuf, woT, pp);
    reduce_relu<<<dim3(1024), blk, 0, stream>>>(pp, out);
}

// Round 5
// 218.920 us; speedup vs baseline: 3.8187x; 1.2052x over previous
//
#include <hip/hip_runtime.h>
#include <math.h>

// Problem: B=4, S=1024, F=256, H=8, FH=2048. SCALE=16 (multiplies logits).
#define SQ 1024
#define FQ 256
#define FH 2048

typedef _Float16 f16;
typedef f16  f16x8 __attribute__((ext_vector_type(8)));
typedef float f32x4 __attribute__((ext_vector_type(4)));

// Async global->LDS, 16 B/lane. LDS dest = wave-uniform base + lane*16.
#define GLOAD_LDS16(gp, lp) \
    __builtin_amdgcn_global_load_lds((const __attribute__((address_space(1))) void*)(gp), \
                                     (__attribute__((address_space(3))) void*)(lp), 16, 0, 0)

// ---------------------------------------------------------------------------
// fp32 -> f16 convert (x input).
// ---------------------------------------------------------------------------
__global__ __launch_bounds__(256) void cvt_kernel(const float* __restrict__ in,
                                                  f16* __restrict__ out) {
    int idx = (blockIdx.x * 256 + threadIdx.x) * 4;
    float4 v = *(const float4*)(in + idx);
    out[idx + 0] = (f16)v.x; out[idx + 1] = (f16)v.y;
    out[idx + 2] = (f16)v.z; out[idx + 3] = (f16)v.w;
}

// ---------------------------------------------------------------------------
// Transpose+convert W (256 x 2048 fp32) -> WT (2048 x 256 f16). z picks matrix.
// ---------------------------------------------------------------------------
__global__ __launch_bounds__(256) void transpose_qkv(const float* __restrict__ W0,
                                                     const float* __restrict__ W1,
                                                     const float* __restrict__ W2,
                                                     f16* __restrict__ T0,
                                                     f16* __restrict__ T1,
                                                     f16* __restrict__ T2) {
    const float* W = blockIdx.z == 0 ? W0 : (blockIdx.z == 1 ? W1 : W2);
    f16* WT        = blockIdx.z == 0 ? T0 : (blockIdx.z == 1 ? T1 : T2);
    __shared__ f16 T[32][33];
    const int tx = threadIdx.x & 31, ty = threadIdx.x >> 5;
    const int n0 = blockIdx.x * 32, k0 = blockIdx.y * 32;
#pragma unroll
    for (int i = 0; i < 4; ++i)
        T[ty + i * 8][tx] = (f16)W[(size_t)(k0 + ty + i * 8) * FH + n0 + tx];
    __syncthreads();
#pragma unroll
    for (int i = 0; i < 4; ++i)
        WT[(size_t)(n0 + ty + i * 8) * FQ + k0 + tx] = T[tx][ty + i * 8];
}

// ---------------------------------------------------------------------------
// Wo (2048 x 256 fp32, row fh = f*8+h) -> WoT (256 x 2048 f16) with k
// PERMUTED to h*256+f (matches new WV layout). grid (8 n-tiles, 64 = ft*8+h).
// ---------------------------------------------------------------------------
__global__ __launch_bounds__(256) void transpose_wo(const float* __restrict__ W,
                                                    f16* __restrict__ WT) {
    __shared__ f16 T[32][33];
    const int tx = threadIdx.x & 31, ty = threadIdx.x >> 5;
    const int n0 = blockIdx.x * 32;
    const int ft = blockIdx.y >> 3, h = blockIdx.y & 7;
#pragma unroll
    for (int i = 0; i < 4; ++i) {
        int fl = ty + i * 8;
        T[fl][tx] = (f16)W[(size_t)((ft * 32 + fl) * 8 + h) * FQ + n0 + tx];
    }
    __syncthreads();
#pragma unroll
    for (int i = 0; i < 4; ++i)
        WT[(size_t)(n0 + ty + i * 8) * FH + h * 256 + ft * 32 + tx] = T[tx][ty + i * 8];
}

// ---------------------------------------------------------------------------
// m97-style staging: (nregions*16) rows x 32 f16, row stride 32, unswizzled.
// ---------------------------------------------------------------------------
__device__ __forceinline__ void stage_rows32(const f16* __restrict__ G, int ldg,
                                             int row0, int k0, f16* S,
                                             int nregions, int w, int lane) {
#pragma unroll
    for (int rI = w; rI < nregions; rI += 4) {
        int r = rI * 16 + (lane >> 2);
        int col = (lane & 3) << 3;
        GLOAD_LDS16(G + (size_t)(row0 + r) * ldg + k0 + col, S + rI * 512);
    }
}

// ---------------------------------------------------------------------------
// Swizzled staging, row stride 256 f16: 2 rows/inst, granule g' = g^(r&7).
// ---------------------------------------------------------------------------
__device__ __forceinline__ void stage_sw256(const f16* __restrict__ G, int ldg,
                                            int row0, f16* S, int nrows,
                                            int w, int lane) {
    const int rsub = lane >> 5;           // 0..1
    const int gl = lane & 31;
#pragma unroll
    for (int rI = w; rI < (nrows >> 1); rI += 4) {
        int r = rI * 2 + rsub;
        int g = gl ^ (r & 7);
        GLOAD_LDS16(G + (size_t)(row0 + r) * ldg + g * 8, S + rI * 512);
    }
}

// ---------------------------------------------------------------------------
// Swizzled staging, row stride 64 f16: 8 rows/inst, granule g' = g^(r&7).
// ---------------------------------------------------------------------------
__device__ __forceinline__ void stage_sw64(const f16* __restrict__ G, int ldg,
                                           int row0, int c0, f16* S,
                                           int nrows, int w, int lane) {
    const int rsub = lane >> 3;           // 0..7
    const int g    = (lane & 7) ^ (rsub & 7);
#pragma unroll
    for (int rI = w; rI < (nrows >> 3); rI += 4) {
        GLOAD_LDS16(G + (size_t)(row0 + rI * 8 + rsub) * ldg + c0 + g * 8,
                    S + rI * 512);
    }
}

// ---------------------------------------------------------------------------
// 128x128 MFMA tile, BK=32. 4 waves 2x2 of 64x64.
// ---------------------------------------------------------------------------
__device__ __forceinline__ void gemm128_lds(const f16* __restrict__ A, int lda,
                                            const f16* __restrict__ Bt, int ldb,
                                            int K, f16* As, f16* Bs,
                                            f32x4 acc[4][4], int row0, int col0) {
    const int t = threadIdx.x, lane = t & 63, w = t >> 6;
    const int wr = w >> 1, wc = w & 1;
    const int lrow = lane & 15, quad = lane >> 4;
    for (int k0 = 0; k0 < K; k0 += 32) {
        __syncthreads();
        stage_rows32(A, lda, row0, k0, As, 8, w, lane);
        stage_rows32(Bt, ldb, col0, k0, Bs, 8, w, lane);
        __syncthreads();
        f16x8 af[4], bf[4];
#pragma unroll
        for (int i = 0; i < 4; ++i) {
            af[i] = *(const f16x8*)&As[(wr * 64 + i * 16 + lrow) * 32 + quad * 8];
            bf[i] = *(const f16x8*)&Bs[(wc * 64 + i * 16 + lrow) * 32 + quad * 8];
        }
#pragma unroll
        for (int i = 0; i < 4; ++i)
#pragma unroll
            for (int j = 0; j < 4; ++j)
                acc[i][j] = __builtin_amdgcn_mfma_f32_16x16x32_f16(af[i], bf[j], acc[i][j], 0, 0, 0);
    }
}

// ---------------------------------------------------------------------------
// Merged QKV projection with coalesced LDS-roundtrip epilogue.
// z=0 Q -> (b,h,s,f); z=1 K -> (b,h,s,f); z=2 V -> (b,h,f,s).
// ---------------------------------------------------------------------------
__global__ __launch_bounds__(256) void proj_mfma(const f16* __restrict__ xh,
                                                 const f16* __restrict__ wqT,
                                                 const f16* __restrict__ wkT,
                                                 const f16* __restrict__ wvT,
                                                 f16* __restrict__ qb,
                                                 f16* __restrict__ kb,
                                                 f16* __restrict__ vb) {
    const int z = blockIdx.z;
    const f16* WT = z == 0 ? wqT : (z == 1 ? wkT : wvT);
    f16* O        = z == 0 ? qb  : (z == 1 ? kb  : vb);
    __shared__ f16 smem[17408];          // As|Bs (8192) then Es (17408) alias
    f16* As = smem;
    f16* Bs = smem + 4096;
    f32x4 acc[4][4] = {};
    const int row0 = blockIdx.y * 128, col0 = blockIdx.x * 128;
    gemm128_lds(xh, FQ, WT, FQ, FQ, As, Bs, acc, row0, col0);

    __syncthreads();                     // As/Bs dead -> reuse as Es
    f16* Es = smem;                      // ld 136
    const int lane = threadIdx.x & 63, w = threadIdx.x >> 6;
    const int wr = w >> 1, wc = w & 1;
    const int lrow = lane & 15, quad = lane >> 4;
    if (z != 2) {
        // Es[row][h*16 + f_local]
#pragma unroll
        for (int i = 0; i < 4; ++i)
#pragma unroll
            for (int rr = 0; rr < 4; ++rr) {
                int rl = 64 * wr + 16 * i + 4 * quad + rr;
#pragma unroll
                for (int j = 0; j < 4; ++j) {
                    int cc = 64 * wc + 16 * j + lrow;
                    Es[rl * 136 + (cc & 7) * 16 + (cc >> 3)] = (f16)acc[i][j][rr];
                }
            }
        __syncthreads();
        const int f0 = col0 >> 3;
#pragma unroll
        for (int it = 0; it < 4; ++it) {
            int c = it * 256 + threadIdx.x;
            int row = c >> 3, hh = c & 7;
            int gr = row0 + row, bbb = gr >> 10, s = gr & 1023;
            f16x8 v0 = *(const f16x8*)&Es[row * 136 + hh * 16];
            f16x8 v1 = *(const f16x8*)&Es[row * 136 + hh * 16 + 8];
            f16* dst = O + ((size_t)(bbb * 8 + hh) * SQ + s) * FQ + f0;
            *(f16x8*)dst = v0;
            *(f16x8*)(dst + 8) = v1;
        }
    } else {
        // Es[cc][row] -> 128 s-contiguous per (h,f)
#pragma unroll
        for (int i = 0; i < 4; ++i)
#pragma unroll
            for (int rr = 0; rr < 4; ++rr) {
                int rl = 64 * wr + 16 * i + 4 * quad + rr;
#pragma unroll
                for (int j = 0; j < 4; ++j) {
                    int cc = 64 * wc + 16 * j + lrow;
                    Es[cc * 136 + rl] = (f16)acc[i][j][rr];
                }
            }
        __syncthreads();
        const int bbb = row0 >> 10, s0 = row0 & 1023;
#pragma unroll
        for (int it = 0; it < 8; ++it) {
            int c = it * 256 + threadIdx.x;
            int cc = c >> 4, sc = c & 15;
            int hh = cc & 7, f = (col0 >> 3) + (cc >> 3);
            f16x8 v = *(const f16x8*)&Es[cc * 136 + sc * 8];
            *(f16x8*)(O + ((size_t)(bbb * 8 + hh) * FQ + f) * SQ + s0 + sc * 8) = v;
        }
    }
}

// ---------------------------------------------------------------------------
// Fused attention v3. Per block: 64 Q-rows of one (b,h); j-tiles of 64.
//  - Q A-frags read straight from global (L2-resident via XCD swizzle).
//  - K_j (64x256) staged in ONE burst (full feature depth) -> QK barrier-free.
//  - V_j (256x64) staged in ONE burst -> PV barrier-free.
//  - 4 barriers / 2 vmcnt drains per j-tile. LDS 41 KB -> 3 blocks/CU.
// Output WV layout: [b*S+s][h*256+f] (512 B contiguous rows per block).
// ---------------------------------------------------------------------------
__global__ __launch_bounds__(256) void fused_attn(const f16* __restrict__ Qb,
                                                  const f16* __restrict__ Kb,
                                                  const f16* __restrict__ Vt,
                                                  f16* __restrict__ WV) {
    __shared__ f16 smem[20992];          // KVs 16384 | Ps 4608; Es(16896) alias
    f16* KVs = smem;
    f16* Ps  = smem + 16384;             // 64 x 72
    const int t = threadIdx.x, lane = t & 63, w = t >> 6;
    const int wr = w >> 1, wc = w & 1;
    const int lrow = lane & 15, quad = lane >> 4;
    // XCD swizzle: 4 consecutive heads per XCD -> K/V/Q L2-resident per XCD.
    const int n = blockIdx.x;
    const int xcd = n & 7, rest = n >> 3;
    const int bh = xcd * 4 + (rest & 3);
    const int strip = rest >> 2;                 // 0..15
    const int m0 = strip * 64;
    const int bb = bh >> 3, h = bh & 7;
    const f16* Qg = Qb + (size_t)bh * SQ * FQ;   // (s,f)
    const f16* Kg = Kb + (size_t)bh * SQ * FQ;   // (s,f)
    const f16* Vg = Vt + (size_t)bh * FQ * SQ;   // (f,s)

    f32x4 acc_o[2][8] = {};   // rows 32wr+16mi(+4quad+rr), f = 128wc+16nj+lrow

    for (int j0 = 0; j0 < SQ; j0 += 64) {
        __syncthreads();                         // prev V reads done
        stage_sw256(Kg, FQ, j0, KVs, 64, w, lane);
        __syncthreads();                         // K ready (drain)
        // ---- QK^T: S(64x64), waves 2x2 over 32x32; K-dim = 256 ----
        f32x4 acc_s[2][2] = {};
#pragma unroll
        for (int ks = 0; ks < 8; ++ks) {
            f16x8 af[2], bf[2];
#pragma unroll
            for (int mi = 0; mi < 2; ++mi)
                af[mi] = *(const f16x8*)(Qg + (size_t)(m0 + 32 * wr + 16 * mi + lrow) * FQ
                                             + ks * 32 + quad * 8);
#pragma unroll
            for (int nj = 0; nj < 2; ++nj) {
                int r = 32 * wc + 16 * nj + lrow;
                bf[nj] = *(const f16x8*)&KVs[r * 256 + (((ks * 4 + quad) ^ (r & 7)) << 3)];
            }
#pragma unroll
            for (int mi = 0; mi < 2; ++mi)
#pragma unroll
                for (int nj = 0; nj < 2; ++nj)
                    acc_s[mi][nj] = __builtin_amdgcn_mfma_f32_16x16x32_f16(
                        af[mi], bf[nj], acc_s[mi][nj], 0, 0, 0);
        }
        // ---- sigmoid -> Ps (ld 72: conflict-free frag reads) ----
#pragma unroll
        for (int mi = 0; mi < 2; ++mi)
#pragma unroll
            for (int nj = 0; nj < 2; ++nj)
#pragma unroll
                for (int rr = 0; rr < 4; ++rr) {
                    int prow = 32 * wr + 16 * mi + 4 * quad + rr;
                    int pcol = 32 * wc + 16 * nj + lrow;
                    Ps[prow * 72 + pcol] =
                        (f16)(1.0f / (1.0f + __expf(-16.0f * acc_s[mi][nj][rr])));
                }
        __syncthreads();                         // Ps ready + K reads done
        stage_sw64(Vg, SQ, 0, j0, KVs, 256, w, lane);
        __syncthreads();                         // V ready (drain)
        // ---- PV: WV(64x256) += P(64x64) @ V^T ----
        f16x8 ap[2][2];
#pragma unroll
        for (int mi = 0; mi < 2; ++mi)
#pragma unroll
            for (int kf = 0; kf < 2; ++kf)
                ap[mi][kf] = *(const f16x8*)&Ps[(32 * wr + 16 * mi + lrow) * 72
                                                + kf * 32 + quad * 8];
#pragma unroll
        for (int nj = 0; nj < 8; ++nj) {
            int f = 128 * wc + 16 * nj + lrow;
            f16x8 bv0 = *(const f16x8*)&KVs[f * 64 + ((quad ^ (f & 7)) << 3)];
            f16x8 bv1 = *(const f16x8*)&KVs[f * 64 + (((4 + quad) ^ (f & 7)) << 3)];
#pragma unroll
            for (int mi = 0; mi < 2; ++mi) {
                acc_o[mi][nj] = __builtin_amdgcn_mfma_f32_16x16x32_f16(
                    ap[mi][0], bv0, acc_o[mi][nj], 0, 0, 0);
                acc_o[mi][nj] = __builtin_amdgcn_mfma_f32_16x16x32_f16(
                    ap[mi][1], bv1, acc_o[mi][nj], 0, 0, 0);
            }
        }
    }
    // ---- epilogue: LDS roundtrip -> 512 B contiguous rows ----
    __syncthreads();                             // KVs/Ps dead
    f16* Es = smem;                              // 64 x 264
#pragma unroll
    for (int mi = 0; mi < 2; ++mi)
#pragma unroll
        for (int nj = 0; nj < 8; ++nj)
#pragma unroll
            for (int rr = 0; rr < 4; ++rr)
                Es[(32 * wr + 16 * mi + 4 * quad + rr) * 264 + 128 * wc + 16 * nj + lrow] =
                    (f16)acc_o[mi][nj][rr];
    __syncthreads();
#pragma unroll
    for (int it = 0; it < 8; ++it) {
        int c = it * 256 + t;
        int r = c >> 5, ck = c & 31;
        f16x8 v = *(const f16x8*)&Es[r * 264 + ck * 8];
        *(f16x8*)(WV + (size_t)(bb * SQ + m0 + r) * FH + h * 256 + ck * 8) = v;
    }
}

// ---------------------------------------------------------------------------
// out projection, split-K x2 over k = h*256+f. 64x64 tiles, grid (4, 64, 2).
// ---------------------------------------------------------------------------
__global__ __launch_bounds__(256) void out_split(const f16* __restrict__ WVm,
                                                 const f16* __restrict__ WoT,
                                                 float* __restrict__ PP) {
    __shared__ f16 As[64 * 32];
    __shared__ f16 Bs[64 * 32];
    const int t = threadIdx.x, lane = t & 63, w = t >> 6;
    const int wr = w >> 1, wc = w & 1;
    const int lrow = lane & 15, quad = lane >> 4;
    const int row0 = blockIdx.y * 64, col0 = blockIdx.x * 64;
    const int kbase = blockIdx.z * 1024;
    f32x4 acc[2][2] = {};
    for (int k0 = 0; k0 < 1024; k0 += 32) {
        __syncthreads();
        stage_rows32(WVm, FH, row0, kbase + k0, As, 4, w, lane);
        stage_rows32(WoT, FH, col0, kbase + k0, Bs, 4, w, lane);
        __syncthreads();
        f16x8 af[2], bf[2];
#pragma unroll
        for (int i = 0; i < 2; ++i) {
            af[i] = *(const f16x8*)&As[(wr * 32 + i * 16 + lrow) * 32 + quad * 8];
            bf[i] = *(const f16x8*)&Bs[(wc * 32 + i * 16 + lrow) * 32 + quad * 8];
        }
#pragma unroll
        for (int i = 0; i < 2; ++i)
#pragma unroll
            for (int j = 0; j < 2; ++j)
                acc[i][j] = __builtin_amdgcn_mfma_f32_16x16x32_f16(af[i], bf[j], acc[i][j], 0, 0, 0);
    }
    float* P = PP + (size_t)blockIdx.z * SQ * 4 * FQ;
#pragma unroll
    for (int i = 0; i < 2; ++i)
#pragma unroll
        for (int r = 0; r < 4; ++r) {
            int gr = row0 + wr * 32 + i * 16 + quad * 4 + r;
#pragma unroll
            for (int j = 0; j < 2; ++j) {
                int gc = col0 + wc * 32 + j * 16 + lrow;
                P[(size_t)gr * FQ + gc] = acc[i][j][r];
            }
        }
}

__global__ __launch_bounds__(256) void reduce_relu(const float* __restrict__ PP,
                                                   float* __restrict__ O) {
    int idx = (blockIdx.x * 256 + threadIdx.x) * 4;
    f32x4 a = *(const f32x4*)(PP + idx);
    f32x4 b = *(const f32x4*)(PP + 1048576 + idx);
    f32x4 s = a + b;
    f32x4 r = {fmaxf(s.x, 0.f), fmaxf(s.y, 0.f), fmaxf(s.z, 0.f), fmaxf(s.w, 0.f)};
    *(f32x4*)(O + idx) = r;
}

// ---------------------------------------------------------------------------
extern "C" void kernel_launch(void* const* d_in, const int* in_sizes, int n_in,
                              void* d_out, int out_size, void* d_ws, size_t ws_size,
                              hipStream_t stream) {
    const float* x  = (const float*)d_in[0];
    const float* Wq = (const float*)d_in[1];
    const float* Wk = (const float*)d_in[2];
    const float* Wv = (const float*)d_in[3];
    const float* Wo = (const float*)d_in[4];
    float* out = (float*)d_out;

    f16* ws = (f16*)d_ws;
    f16* xh    = ws;                       // 1,048,576
    f16* wqT   = xh    + 1048576;          // 524,288
    f16* wkT   = wqT   + 524288;
    f16* wvT   = wkT   + 524288;
    f16* woT   = wvT   + 524288;           // 524,288 (k permuted to h*256+f)
    f16* qbuf  = woT   + 524288;           // 8,388,608 (b,h,s,f)
    f16* kbuf  = qbuf  + 8388608;          // (b,h,s,f)
    f16* vbuf  = kbuf  + 8388608;          // (b,h,f,s)
    f16* wvbuf = vbuf  + 8388608;          // (b*s, h*256+f)
    float* pp  = (float*)(wvbuf + 8388608);// 2 x 1,048,576 fp32 partials

    dim3 blk(256);
    cvt_kernel<<<dim3(1024), blk, 0, stream>>>(x, xh);
    transpose_qkv<<<dim3(64, 8, 3), blk, 0, stream>>>(Wq, Wk, Wv, wqT, wkT, wvT);
    transpose_wo<<<dim3(8, 64), blk, 0, stream>>>(Wo, woT);

    proj_mfma<<<dim3(16, 32, 3), blk, 0, stream>>>(xh, wqT, wkT, wvT, qbuf, kbuf, vbuf);

    fused_attn<<<dim3(512), blk, 0, stream>>>(qbuf, kbuf, vbuf, wvbuf);

    out_split<<<dim3(4, 64, 2), blk, 0, stream>>>(wvbuf, woT, pp);
    reduce_relu<<<dim3(1024), blk, 0, stream>>>(pp, out);
}